// Round 5
// baseline (94539.917 us; speedup 1.0000x reference)
//
#include <hip/hip_runtime.h>
#include <math.h>

#define HDIM 1024
#define NTAG 256
#define BSZ 128
#define TLEN 50
#define G3 3072
#define NBLK 256

typedef unsigned long long u64;

// ---- static f32 pool ----
constexpr u64 GX_F  = (u64)TLEN*G3*BSZ;     // gx_t [t][n][b]
constexpr u64 SEQ_F = (u64)TLEN*BSZ*HDIM;   // [t][b][k]
constexpr u64 HST_F = (u64)BSZ*HDIM;
constexpr u64 F_GX  = 0;
constexpr u64 F_OF0 = F_GX + GX_F;
constexpr u64 F_OB0 = F_OF0 + SEQ_F;
constexpr u64 F_ENC = F_OB0 + SEQ_F;
constexpr u64 F_HZ0 = F_ENC + SEQ_F;
constexpr u64 F_HZ1 = F_HZ0 + HST_F;
constexpr u64 F_HZ2 = F_HZ1 + HST_F;
constexpr u64 F_HZ3 = F_HZ2 + HST_F;
constexpr u64 F_HT  = F_HZ3 + HST_F;
constexpr u64 F_D0A = F_HT + HST_F;
constexpr u64 F_D0B = F_D0A + HST_F;
constexpr u64 F_D1A = F_D0B + HST_F;
constexpr u64 F_D1B = F_D1A + HST_F;
constexpr u64 F_CTX = F_D1B + HST_F;
constexpr u64 F_CC  = F_CTX + HST_F;
constexpr u64 F_SC  = F_CC + HST_F;            // scores [50][128]
constexpr u64 F_LG  = F_SC + (u64)TLEN*BSZ;    // logits [128][256]
constexpr u64 F_NLL = F_LG + (u64)BSZ*NTAG;    // nll [50][128]
constexpr u64 POOL_F = F_NLL + (u64)TLEN*BSZ;

__device__ __align__(256) float g_pool[POOL_F];
__device__ unsigned g_bar_cnt = 0;
__device__ unsigned g_bar_gen = 0;

__device__ __forceinline__ float sigmf(float x){ return 1.f/(1.f+__expf(-x)); }

// software grid barrier; safe: grid==NBLK<=256 CUs, LDS<=40KB, lb(256,2) => co-resident
__device__ __forceinline__ void grid_sync(){
  __syncthreads();
  if (threadIdx.x == 0){
    __threadfence();
    unsigned gen = __hip_atomic_load(&g_bar_gen, __ATOMIC_RELAXED, __HIP_MEMORY_SCOPE_AGENT);
    unsigned old = __hip_atomic_fetch_add(&g_bar_cnt, 1u, __ATOMIC_ACQ_REL, __HIP_MEMORY_SCOPE_AGENT);
    if (old == (unsigned)(NBLK-1)){
      __hip_atomic_store(&g_bar_cnt, 0u, __ATOMIC_RELAXED, __HIP_MEMORY_SCOPE_AGENT);
      __hip_atomic_fetch_add(&g_bar_gen, 1u, __ATOMIC_ACQ_REL, __HIP_MEMORY_SCOPE_AGENT);
    } else {
      while (__hip_atomic_load(&g_bar_gen, __ATOMIC_ACQUIRE, __HIP_MEMORY_SCOPE_AGENT) == gen)
        __builtin_amdgcn_s_sleep(2);
    }
    __threadfence();
  }
  __syncthreads();
}

// stage [128 rows][32 k] tile (global row stride HDIM) into dst[128][33]
__device__ __forceinline__ void stage128x32(float (*dst)[33], const float* __restrict__ src_base, int tid){
  const int b = tid>>1, seg = tid&1;
  const float* s = src_base + (u64)b*HDIM + seg*16;
  float* d = &dst[b][seg*16];
  float4 v0 = *(const float4*)(s+0);
  float4 v1 = *(const float4*)(s+4);
  float4 v2 = *(const float4*)(s+8);
  float4 v3 = *(const float4*)(s+12);
  *(float4*)(d+0)=v0; *(float4*)(d+4)=v1; *(float4*)(d+8)=v2; *(float4*)(d+12)=v3;
}

// stage 12 weight rows (3 gates x 4 j) x 32 k: row (r>>2)*HDIM + j0 + (r&3), W row stride K
__device__ __forceinline__ void stage_w12(float (*ws)[33], const float* __restrict__ W, int j0, int k0, int K, int tid){
  if (tid < 96){
    const int r = tid>>3, q = tid&7;
    const int row = (r>>2)*HDIM + j0 + (r&3);
    *(float4*)&ws[r][q*4] = *(const float4*)&W[(u64)row*K + k0 + q*4];
  }
}

__device__ __forceinline__ void gru_acc(const float (*hs)[33], const float (*ws)[33], int j, int lane, float acc[2][3]){
  #pragma unroll
  for (int kk=0; kk<32; kk+=4){
    float4 w0 = *(const float4*)&ws[j][kk];
    float4 w1 = *(const float4*)&ws[4+j][kk];
    float4 w2 = *(const float4*)&ws[8+j][kk];
    float4 ha = *(const float4*)&hs[lane][kk];
    float4 hb = *(const float4*)&hs[lane+64][kk];
    acc[0][0] += ha.x*w0.x + ha.y*w0.y + ha.z*w0.z + ha.w*w0.w;
    acc[0][1] += ha.x*w1.x + ha.y*w1.y + ha.z*w1.z + ha.w*w1.w;
    acc[0][2] += ha.x*w2.x + ha.y*w2.y + ha.z*w2.z + ha.w*w2.w;
    acc[1][0] += hb.x*w0.x + hb.y*w0.y + hb.z*w0.z + hb.w*w0.w;
    acc[1][1] += hb.x*w1.x + hb.y*w1.y + hb.z*w1.z + hb.w*w1.w;
    acc[1][2] += hb.x*w2.x + hb.y*w2.y + hb.z*w2.z + hb.w*w2.w;
  }
}

#define AM_ENC 0
#define AM_DEC 1
#define AM_CAT 2

// gx_t[(t*G3 + n)*BSZ + b] = A[t,b,:] @ W[n,:] + bias[n]   (transposed output via LDS)
template<int AMODE>
__global__ __launch_bounds__(256)
void gemm_gx(const float* __restrict__ embed,
             u64 a1_f, u64 a2_f,
             const int* __restrict__ ids,
             const float* __restrict__ W,
             const float* __restrict__ bias,
             u64 c_f, int K)
{
  constexpr int TM=128, TN=64, TK=32;
  __shared__ float As[TK][TM+4];
  __shared__ float Ws[TK][TN+4];
  __shared__ int rowid[TM];
  const int t = blockIdx.x;          // TM==BSZ => one t per x-block
  const int m0 = t*TM, n0 = blockIdx.y*TN;
  const int tid = threadIdx.x;

  if (AMODE != AM_CAT){
    for (int r=tid; r<TM; r+=256){
      rowid[r] = (AMODE==AM_ENC) ? ids[r*TLEN+t] : ((t==0)?1:ids[r*TLEN+t-1]);
    }
    __syncthreads();
  }

  const int tm = tid>>4, tn = tid&15;
  float acc[8][4];
  #pragma unroll
  for (int i=0;i<8;i++){ acc[i][0]=0.f;acc[i][1]=0.f;acc[i][2]=0.f;acc[i][3]=0.f; }

  for (int k0=0;k0<K;k0+=TK){
    if (AMODE==AM_CAT){
      const float* Asrc = g_pool + ((k0<HDIM)? a1_f : a2_f);
      const int kb = (k0<HDIM)? k0 : k0-HDIM;
      #pragma unroll
      for (int l=tid; l<TM*TK; l+=256){
        int r=l>>5, k=l&31;
        As[k][r] = Asrc[(u64)(m0+r)*HDIM + kb + k];
      }
    } else {
      #pragma unroll
      for (int l=tid; l<TM*TK; l+=256){
        int r=l>>5, k=l&31;
        As[k][r] = embed[(u64)rowid[r]*HDIM + k0 + k];
      }
    }
    #pragma unroll
    for (int l=tid; l<TN*TK; l+=256){
      int n=l>>5, k=l&31;
      Ws[k][n] = W[(u64)(n0+n)*K + k0 + k];
    }
    __syncthreads();
    #pragma unroll 8
    for (int kk=0;kk<TK;kk++){
      float4 a0 = *(const float4*)&As[kk][tm*8];
      float4 a1 = *(const float4*)&As[kk][tm*8+4];
      float4 w  = *(const float4*)&Ws[kk][tn*4];
      float av[8]={a0.x,a0.y,a0.z,a0.w,a1.x,a1.y,a1.z,a1.w};
      float wv[4]={w.x,w.y,w.z,w.w};
      #pragma unroll
      for (int i=0;i<8;i++){
        #pragma unroll
        for (int jj=0;jj<4;jj++) acc[i][jj] += av[i]*wv[jj];
      }
    }
    __syncthreads();
  }

  float bv[4];
  #pragma unroll
  for (int jj=0;jj<4;jj++) bv[jj] = bias[n0+tn*4+jj];
  float* C = g_pool + c_f;
  // transpose epilogue: two halves of 32 n-rows through As[32][132]
  for (int half=0; half<2; ++half){
    if ((tn>>3)==half){
      #pragma unroll
      for (int i=0;i<8;i++){
        #pragma unroll
        for (int jj=0;jj<4;jj++)
          As[(tn&7)*4+jj][tm*8+i] = acc[i][jj]+bv[jj];
      }
    }
    __syncthreads();
    {
      const int nn = tid>>3, q = tid&7;
      float* dst = C + ((u64)t*G3 + n0 + half*32 + nn)*BSZ + q*16;
      const float* srow = &As[nn][q*16];
      float4 v0 = *(const float4*)(srow+0);
      float4 v1 = *(const float4*)(srow+4);
      float4 v2 = *(const float4*)(srow+8);
      float4 v3 = *(const float4*)(srow+12);
      *(float4*)(dst+0)=v0; *(float4*)(dst+4)=v1; *(float4*)(dst+8)=v2; *(float4*)(dst+12)=v3;
    }
    __syncthreads();
  }
}

// persistent masked GRU scan: 50 steps, 1 grid barrier per step.
// BWD: iterate t = T-1..0 (== reverse_padded semantics with mask t<len)
template<bool BWD, bool ACCUM>
__global__ __launch_bounds__(256,2)
void scan_kernel(u64 gx_f, u64 hz_f, u64 ht_f,
                 const float* __restrict__ whh, const float* __restrict__ bhh,
                 const int* __restrict__ lengths, u64 out_f)
{
  __shared__ float hs[128][33];
  __shared__ float ws[12][33];
  __shared__ float oh[4][132];
  __shared__ float oo[4][132];
  const int bid = blockIdx.x, tid = threadIdx.x;
  const int j = tid>>6, lane = tid&63;
  const int j0 = bid*4, jg = j0 + j;
  const float bhr = bhh[jg], bhz = bhh[HDIM+jg], bhn = bhh[2*HDIM+jg];
  const int len1 = lengths[lane], len2 = lengths[lane+64];

  for (int s=0; s<TLEN; ++s){
    const int t = BWD ? (TLEN-1-s) : s;
    const u64 rdf = (s&1) ? ht_f : hz_f;   // s=0 writes ht; s odd writes hz => final in hz
    const u64 wrf = (s&1) ? hz_f : ht_f;
    const float* hprev = g_pool + rdf;
    float* hnext = g_pool + wrf;
    float acc[2][3] = {{0.f,0.f,0.f},{0.f,0.f,0.f}};
    if (s > 0){
      for (int kc=0; kc<32; ++kc){
        const int k0 = kc*32;
        stage128x32(hs, hprev + k0, tid);
        stage_w12(ws, whh, j0, k0, HDIM, tid);
        __syncthreads();
        gru_acc(hs, ws, j, lane, acc);
        __syncthreads();
      }
    }
    const float* gbase = g_pool + gx_f + ((u64)t*G3 + jg)*BSZ;
    #pragma unroll
    for (int h2=0; h2<2; ++h2){
      const int b = lane + h2*64;
      const int len = h2 ? len2 : len1;
      const bool m = (t < len);
      const float xr = gbase[b];
      const float xz = gbase[(u64)HDIM*BSZ + b];
      const float xn = gbase[(u64)2*HDIM*BSZ + b];
      const float hp = (s>0) ? oh[j][b] : 0.f;   // own slot from prev step
      const float rg = sigmf(xr + acc[h2][0] + bhr);
      const float zg = sigmf(xz + acc[h2][1] + bhz);
      const float ng = tanhf(xn + rg*(acc[h2][2] + bhn));
      const float hv = (1.f-zg)*ng + zg*hp;
      oh[j][b] = m ? hv : hp;
      oo[j][b] = m ? hv : 0.f;
    }
    __syncthreads();
    if (tid < 128){
      float4 vh; vh.x=oh[0][tid]; vh.y=oh[1][tid]; vh.z=oh[2][tid]; vh.w=oh[3][tid];
      *(float4*)&hnext[(u64)tid*HDIM + j0] = vh;
      float* op = g_pool + out_f + ((u64)t*BSZ + tid)*HDIM + j0;
      float4 vo; vo.x=oo[0][tid]; vo.y=oo[1][tid]; vo.z=oo[2][tid]; vo.w=oo[3][tid];
      if (ACCUM){
        float4 e = *(float4*)op;
        vo.x+=e.x; vo.y+=e.y; vo.z+=e.z; vo.w+=e.w;
      }
      *(float4*)op = vo;
    }
    grid_sync();
  }
}

// persistent decoder: 50 steps x 6 phases
__global__ __launch_bounds__(256,2)
void decoder_kernel(const float* __restrict__ whh0, const float* __restrict__ bhh0,
                    const float* __restrict__ wih1, const float* __restrict__ bih1,
                    const float* __restrict__ whh1, const float* __restrict__ bhh1,
                    const float* __restrict__ cw, const float* __restrict__ cb,
                    const float* __restrict__ ow, const float* __restrict__ ob,
                    const int* __restrict__ tag_ids, const int* __restrict__ lengths,
                    float* __restrict__ dout)
{
  __shared__ union {
    struct { float hs[128][33]; float ws[12][33]; float oh[4][132]; } p1;
    struct { float hs0[128][33]; float hs1[128][33]; float wa[12][33]; float wb[12][33]; float oh[4][132]; } p2;
    struct { float es[128][33]; float hs[128][33]; float part[256]; } p3;
    struct { float a[64]; } p4;
    struct { float hs[128][33]; float ws[4][33]; float oh[4][132]; } p5;
    struct { float wf[4][1024]; float cs[128][33]; float og[4][132]; } p6;
    struct { float lgs[256]; float red[256]; } p7;
  } sm;

  const int bid = blockIdx.x, tid = threadIdx.x;
  const int j = tid>>6, lane = tid&63;
  const int j0 = bid*4, jg = j0 + j;

  for (int t=0; t<TLEN; ++t){
    const u64 h0c = (t==0)? F_HZ0 : ((t&1)? F_D0A : F_D0B);
    const u64 h0n = (t&1)? F_D0B : F_D0A;
    const u64 h1c = (t==0)? F_HZ1 : ((t&1)? F_D1A : F_D1B);
    const u64 h1n = (t&1)? F_D1B : F_D1A;

    // ---- P1: decoder layer-0 GRU ----
    {
      const float* hprev = g_pool + h0c;
      float acc[2][3] = {{0.f,0.f,0.f},{0.f,0.f,0.f}};
      for (int kc=0;kc<32;++kc){
        const int k0 = kc*32;
        stage128x32(sm.p1.hs, hprev + k0, tid);
        stage_w12(sm.p1.ws, whh0, j0, k0, HDIM, tid);
        __syncthreads();
        gru_acc(sm.p1.hs, sm.p1.ws, j, lane, acc);
        __syncthreads();
      }
      const float* gbase = g_pool + F_GX + ((u64)t*G3 + jg)*BSZ;
      const float bhr = bhh0[jg], bhz = bhh0[HDIM+jg], bhn = bhh0[2*HDIM+jg];
      #pragma unroll
      for (int h2=0; h2<2; ++h2){
        const int b = lane + h2*64;
        const float xr = gbase[b], xz = gbase[(u64)HDIM*BSZ+b], xn = gbase[(u64)2*HDIM*BSZ+b];
        const float hp = hprev[(u64)b*HDIM + jg];
        const float rg = sigmf(xr + acc[h2][0] + bhr);
        const float zg = sigmf(xz + acc[h2][1] + bhz);
        const float ng = tanhf(xn + rg*(acc[h2][2] + bhn));
        sm.p1.oh[j][b] = (1.f-zg)*ng + zg*hp;
      }
      __syncthreads();
      if (tid < 128){
        float* hn = g_pool + h0n;
        float4 v; v.x=sm.p1.oh[0][tid]; v.y=sm.p1.oh[1][tid]; v.z=sm.p1.oh[2][tid]; v.w=sm.p1.oh[3][tid];
        *(float4*)&hn[(u64)tid*HDIM + j0] = v;
      }
    }
    grid_sync();

    // ---- P2: gxd1 = h0new @ wih1^T, fused with layer-1 GRU ----
    {
      const float* h0new = g_pool + h0n;
      const float* h1prev = g_pool + h1c;
      float aX[2][3] = {{0.f,0.f,0.f},{0.f,0.f,0.f}};
      float aH[2][3] = {{0.f,0.f,0.f},{0.f,0.f,0.f}};
      for (int kc=0;kc<32;++kc){
        const int k0 = kc*32;
        stage128x32(sm.p2.hs0, h0new + k0, tid);
        stage128x32(sm.p2.hs1, h1prev + k0, tid);
        stage_w12(sm.p2.wa, wih1, j0, k0, HDIM, tid);
        if (tid >= 96 && tid < 192){
          const int tt = tid - 96;
          const int r = tt>>3, q = tt&7;
          const int row = (r>>2)*HDIM + j0 + (r&3);
          *(float4*)&sm.p2.wb[r][q*4] = *(const float4*)&whh1[(u64)row*HDIM + k0 + q*4];
        }
        __syncthreads();
        gru_acc(sm.p2.hs0, sm.p2.wa, j, lane, aX);
        gru_acc(sm.p2.hs1, sm.p2.wb, j, lane, aH);
        __syncthreads();
      }
      const float bxr = bih1[jg], bxz = bih1[HDIM+jg], bxn = bih1[2*HDIM+jg];
      const float bhr = bhh1[jg], bhz = bhh1[HDIM+jg], bhn = bhh1[2*HDIM+jg];
      #pragma unroll
      for (int h2=0; h2<2; ++h2){
        const int b = lane + h2*64;
        const float hp = h1prev[(u64)b*HDIM + jg];
        const float rg = sigmf(aX[h2][0] + bxr + aH[h2][0] + bhr);
        const float zg = sigmf(aX[h2][1] + bxz + aH[h2][1] + bhz);
        const float ng = tanhf(aX[h2][2] + bxn + rg*(aH[h2][2] + bhn));
        sm.p2.oh[j][b] = (1.f-zg)*ng + zg*hp;
      }
      __syncthreads();
      if (tid < 128){
        float* hn = g_pool + h1n;
        float4 v; v.x=sm.p2.oh[0][tid]; v.y=sm.p2.oh[1][tid]; v.z=sm.p2.oh[2][tid]; v.w=sm.p2.oh[3][tid];
        *(float4*)&hn[(u64)tid*HDIM + j0] = v;
      }
    }
    grid_sync();

    // ---- P3: scores[t'][b] = h1 . enc[t',b,:] ----
    if (bid < TLEN){
      const int tp = bid;
      const float* encb = g_pool + F_ENC + (u64)tp*BSZ*HDIM;
      const float* h1new = g_pool + h1n;
      float a0 = 0.f;
      const int b3 = tid>>1, half = tid&1;
      for (int kc=0;kc<32;++kc){
        const int k0 = kc*32;
        stage128x32(sm.p3.es, encb + k0, tid);
        stage128x32(sm.p3.hs, h1new + k0, tid);
        __syncthreads();
        #pragma unroll
        for (int u=0; u<16; u+=4){
          float4 e4 = *(const float4*)&sm.p3.es[b3][half*16+u];
          float4 h4 = *(const float4*)&sm.p3.hs[b3][half*16+u];
          a0 += e4.x*h4.x + e4.y*h4.y + e4.z*h4.z + e4.w*h4.w;
        }
        __syncthreads();
      }
      sm.p3.part[tid] = a0;
      __syncthreads();
      if (tid < 128)
        g_pool[F_SC + (u64)tp*BSZ + tid] = sm.p3.part[tid*2] + sm.p3.part[tid*2+1];
    }
    grid_sync();

    // ---- P4: softmax over t' + ctx[b][k] ----
    if (bid < BSZ){
      const int b = bid;
      if (tid < 64){
        float v = (tid < TLEN) ? g_pool[F_SC + (u64)tid*BSZ + b] : -1e30f;
        float mx = v;
        #pragma unroll
        for (int o=32;o;o>>=1) mx = fmaxf(mx, __shfl_xor(mx, o));
        float e = (tid < TLEN) ? __expf(v - mx) : 0.f;
        float ssum = e;
        #pragma unroll
        for (int o=32;o;o>>=1) ssum += __shfl_xor(ssum, o);
        if (tid < TLEN) sm.p4.a[tid] = e / ssum;
      }
      __syncthreads();
      const int k = tid*4;
      float4 ac = {0.f,0.f,0.f,0.f};
      for (int tp=0; tp<TLEN; ++tp){
        const float a = sm.p4.a[tp];
        float4 e4 = *(const float4*)(g_pool + F_ENC + ((u64)tp*BSZ + b)*HDIM + k);
        ac.x += a*e4.x; ac.y += a*e4.y; ac.z += a*e4.z; ac.w += a*e4.w;
      }
      *(float4*)(g_pool + F_CTX + (u64)b*HDIM + k) = ac;
    }
    grid_sync();

    // ---- P5: cc = tanh([h1,ctx] @ cw^T + cb) ----
    {
      const int n = jg;
      const float* h1new = g_pool + h1n;
      float acc2[2] = {0.f, 0.f};
      for (int kc=0;kc<64;++kc){
        const int k0 = (kc&31)*32;
        const float* src = (kc<32) ? h1new : (g_pool + F_CTX);
        stage128x32(sm.p5.hs, src + k0, tid);
        if (tid < 32){
          const int r = tid>>3, q = tid&7;
          const int kgl = (kc<32)? k0 : (HDIM + k0);
          *(float4*)&sm.p5.ws[r][q*4] = *(const float4*)&cw[(u64)(j0+r)*(2*HDIM) + kgl + q*4];
        }
        __syncthreads();
        #pragma unroll
        for (int kk=0; kk<32; kk+=4){
          float4 w4 = *(const float4*)&sm.p5.ws[j][kk];
          float4 ha = *(const float4*)&sm.p5.hs[lane][kk];
          float4 hb = *(const float4*)&sm.p5.hs[lane+64][kk];
          acc2[0] += ha.x*w4.x + ha.y*w4.y + ha.z*w4.z + ha.w*w4.w;
          acc2[1] += hb.x*w4.x + hb.y*w4.y + hb.z*w4.z + hb.w*w4.w;
        }
        __syncthreads();
      }
      const float cbv = cb[n];
      sm.p5.oh[j][lane]    = tanhf(acc2[0] + cbv);
      sm.p5.oh[j][lane+64] = tanhf(acc2[1] + cbv);
      __syncthreads();
      if (tid < 128){
        float4 v; v.x=sm.p5.oh[0][tid]; v.y=sm.p5.oh[1][tid]; v.z=sm.p5.oh[2][tid]; v.w=sm.p5.oh[3][tid];
        *(float4*)(g_pool + F_CC + (u64)tid*HDIM + j0) = v;
      }
    }
    grid_sync();

    // ---- P6a: logits[b][v] = cc . ow[v] + ob[v] ----
    if (bid < 64){
      const int v0 = bid*4;
      {
        const int r = tid>>6, q = tid&63;
        const float* s = ow + (u64)(v0+r)*HDIM + q*16;
        float* d = &sm.p6.wf[r][q*16];
        float4 a0=*(const float4*)(s+0), a1=*(const float4*)(s+4), a2=*(const float4*)(s+8), a3=*(const float4*)(s+12);
        *(float4*)(d+0)=a0; *(float4*)(d+4)=a1; *(float4*)(d+8)=a2; *(float4*)(d+12)=a3;
      }
      float acc2[2] = {0.f,0.f};
      for (int kc=0;kc<32;++kc){
        const int k0 = kc*32;
        stage128x32(sm.p6.cs, g_pool + F_CC + k0, tid);
        __syncthreads();
        #pragma unroll
        for (int kk=0;kk<32;kk+=4){
          float4 w4 = *(const float4*)&sm.p6.wf[j][k0+kk];
          float4 ca = *(const float4*)&sm.p6.cs[lane][kk];
          float4 cb4 = *(const float4*)&sm.p6.cs[lane+64][kk];
          acc2[0] += ca.x*w4.x + ca.y*w4.y + ca.z*w4.z + ca.w*w4.w;
          acc2[1] += cb4.x*w4.x + cb4.y*w4.y + cb4.z*w4.z + cb4.w*w4.w;
        }
        __syncthreads();
      }
      const float obv = ob[v0+j];
      sm.p6.og[j][lane]    = acc2[0] + obv;
      sm.p6.og[j][lane+64] = acc2[1] + obv;
      __syncthreads();
      if (tid < 128){
        float4 v; v.x=sm.p6.og[0][tid]; v.y=sm.p6.og[1][tid]; v.z=sm.p6.og[2][tid]; v.w=sm.p6.og[3][tid];
        *(float4*)(g_pool + F_LG + (u64)tid*NTAG + v0) = v;
      }
    }
    grid_sync();

    // ---- P6b: per-b softmax, store logits + nll ----
    if (bid < BSZ){
      const int b = bid;
      const float lg = g_pool[F_LG + (u64)b*NTAG + tid];
      sm.p7.lgs[tid] = lg;
      sm.p7.red[tid] = lg;
      __syncthreads();
      for (int o=128;o;o>>=1){ if (tid<o) sm.p7.red[tid] = fmaxf(sm.p7.red[tid], sm.p7.red[tid+o]); __syncthreads(); }
      const float mx = sm.p7.red[0];
      __syncthreads();
      sm.p7.red[tid] = __expf(lg - mx);
      __syncthreads();
      for (int o=128;o;o>>=1){ if (tid<o) sm.p7.red[tid] += sm.p7.red[tid+o]; __syncthreads(); }
      const float lse = mx + __logf(sm.p7.red[0]);
      dout[((u64)b*TLEN + t)*NTAG + tid] = lg;
      if (tid == 0){
        const int tag = tag_ids[b*TLEN + t];
        g_pool[F_NLL + (u64)t*BSZ + b] = lse - sm.p7.lgs[tag];
      }
    }
    // no barrier needed before next P1 (disjoint buffers; P6a is 5 barriers away)
  }
  grid_sync();
  // ---- loss ----
  if (bid == 0){
    float ssum = 0.f;
    for (int i=tid; i<TLEN*BSZ; i+=256){
      const int tt = i>>7, b = i&127;
      if (tt < lengths[b]) ssum += g_pool[F_NLL + i];
    }
    sm.p7.red[tid] = ssum; __syncthreads();
    for (int o=128;o;o>>=1){ if (tid<o) sm.p7.red[tid] += sm.p7.red[tid+o]; __syncthreads(); }
    if (tid == 0){
      int den = 0;
      for (int b=0;b<BSZ;b++) den += lengths[b];
      dout[(u64)BSZ*TLEN*NTAG] = sm.p7.red[0] / (float)den;
    }
  }
}

extern "C" void kernel_launch(void* const* d_in, const int* in_sizes, int n_in,
                              void* d_out, int out_size, void* d_ws, size_t ws_size,
                              hipStream_t stream)
{
  const float* enc_embed = (const float*)d_in[0];
  const float* e0_wih = (const float*)d_in[1];
  const float* e0_whh = (const float*)d_in[2];
  const float* e0_bih = (const float*)d_in[3];
  const float* e0_bhh = (const float*)d_in[4];
  const float* e1_wih = (const float*)d_in[5];
  const float* e1_whh = (const float*)d_in[6];
  const float* e1_bih = (const float*)d_in[7];
  const float* e1_bhh = (const float*)d_in[8];
  const float* dec_embed = (const float*)d_in[9];
  const float* d_wih = (const float*)d_in[10];
  const float* d_whh = (const float*)d_in[11];
  const float* d_bih = (const float*)d_in[12];
  const float* d_bhh = (const float*)d_in[13];
  const float* concat_w = (const float*)d_in[14];
  const float* concat_b = (const float*)d_in[15];
  const float* out_w = (const float*)d_in[16];
  const float* out_b = (const float*)d_in[17];
  const int* input_ids = (const int*)d_in[18];
  const int* tag_ids  = (const int*)d_in[19];
  const int* lengths  = (const int*)d_in[20];
  float* dout = (float*)d_out;

  const dim3 gxg(TLEN, G3/64);   // (50,48)

  // encoder L0 fwd
  gemm_gx<AM_ENC><<<gxg,256,0,stream>>>(enc_embed, 0,0, input_ids, e0_wih, e0_bih, F_GX, HDIM);
  scan_kernel<false,false><<<NBLK,256,0,stream>>>(F_GX, F_HZ0, F_HT, e0_whh, e0_bhh, lengths, F_OF0);
  // encoder L0 bwd
  gemm_gx<AM_ENC><<<gxg,256,0,stream>>>(enc_embed, 0,0, input_ids, e0_wih + (u64)G3*HDIM, e0_bih + G3, F_GX, HDIM);
  scan_kernel<true,false><<<NBLK,256,0,stream>>>(F_GX, F_HZ1, F_HT, e0_whh + (u64)G3*HDIM, e0_bhh + G3, lengths, F_OB0);
  // encoder L1 fwd
  gemm_gx<AM_CAT><<<gxg,256,0,stream>>>(nullptr, F_OF0, F_OB0, nullptr, e1_wih, e1_bih, F_GX, 2*HDIM);
  scan_kernel<false,false><<<NBLK,256,0,stream>>>(F_GX, F_HZ2, F_HT, e1_whh, e1_bhh, lengths, F_ENC);
  // encoder L1 bwd (accumulate into enc)
  gemm_gx<AM_CAT><<<gxg,256,0,stream>>>(nullptr, F_OF0, F_OB0, nullptr, e1_wih + (u64)G3*2*HDIM, e1_bih + G3, F_GX, 2*HDIM);
  scan_kernel<true,true><<<NBLK,256,0,stream>>>(F_GX, F_HZ3, F_HT, e1_whh + (u64)G3*HDIM, e1_bhh + G3, lengths, F_ENC);
  // decoder gx + persistent decoder
  gemm_gx<AM_DEC><<<gxg,256,0,stream>>>(dec_embed, 0,0, tag_ids, d_wih, d_bih, F_GX, HDIM);
  decoder_kernel<<<NBLK,256,0,stream>>>(d_whh, d_bhh,
                                        d_wih + (u64)G3*HDIM, d_bih + G3,
                                        d_whh + (u64)G3*HDIM, d_bhh + G3,
                                        concat_w, concat_b, out_w, out_b,
                                        tag_ids, lengths, dout);
}

// Round 7
// 60743.726 us; speedup vs baseline: 1.5564x; 1.5564x over previous
//
#include <hip/hip_runtime.h>
#include <math.h>

#define HDIM 1024
#define NTAG 256
#define BSZ 128
#define TLEN 50
#define G3 3072
#define NBLK 256

typedef unsigned long long u64;

// ---- static f32 pool, all recurrent tensors stored transposed [k][b] ----
constexpr u64 GX_F  = (u64)TLEN*G3*BSZ;     // gx [t][n][b]
constexpr u64 SEQ_F = (u64)TLEN*HDIM*BSZ;   // seq outputs [t][k][b]
constexpr u64 HST_F = (u64)HDIM*BSZ;        // h state [k][b]
constexpr u64 F_GX  = 0;
constexpr u64 F_OF0 = F_GX + GX_F;
constexpr u64 F_OB0 = F_OF0 + SEQ_F;
constexpr u64 F_ENC = F_OB0 + SEQ_F;
constexpr u64 F_T0  = F_ENC + SEQ_F;
constexpr u64 F_T1  = F_T0 + HST_F;
constexpr u64 F_H0F = F_T1 + HST_F;
constexpr u64 F_H0B = F_H0F + HST_F;
constexpr u64 F_D0A = F_H0B + HST_F;
constexpr u64 F_D0B = F_D0A + HST_F;
constexpr u64 F_D1A = F_D0B + HST_F;
constexpr u64 F_D1B = F_D1A + HST_F;
constexpr u64 F_CTX = F_D1B + HST_F;
constexpr u64 F_CC  = F_CTX + HST_F;
constexpr u64 F_PART= F_CC + HST_F;                 // 12*HDIM*BSZ partial pool
constexpr u64 F_P6  = F_PART + (u64)12*HDIM*BSZ;    // 4*NTAG*BSZ logits partials
constexpr u64 F_QP  = F_P6 + (u64)4*NTAG*BSZ;       // 4*TLEN*BSZ score partials
constexpr u64 F_A   = F_QP + (u64)4*TLEN*BSZ;       // attn weights [tp][b]
constexpr u64 F_NLL = F_A + (u64)TLEN*BSZ;
constexpr u64 POOL_F= F_NLL + (u64)TLEN*BSZ;

__device__ __align__(256) float g_pool[POOL_F];
__device__ unsigned g_bar_cnt = 0;
__device__ unsigned g_bar_gen = 0;

__device__ __forceinline__ float sigmf(float x){ return 1.f/(1.f+__expf(-x)); }

// software grid barrier; grid==NBLK==256 <= 256 CUs, LDS<=27KB, lb(256,2) => co-resident
__device__ __forceinline__ void grid_sync(){
  __syncthreads();
  if (threadIdx.x == 0){
    __threadfence();
    unsigned gen = __hip_atomic_load(&g_bar_gen, __ATOMIC_RELAXED, __HIP_MEMORY_SCOPE_AGENT);
    unsigned old = __hip_atomic_fetch_add(&g_bar_cnt, 1u, __ATOMIC_ACQ_REL, __HIP_MEMORY_SCOPE_AGENT);
    if (old == (unsigned)(NBLK-1)){
      __hip_atomic_store(&g_bar_cnt, 0u, __ATOMIC_RELAXED, __HIP_MEMORY_SCOPE_AGENT);
      __hip_atomic_fetch_add(&g_bar_gen, 1u, __ATOMIC_ACQ_REL, __HIP_MEMORY_SCOPE_AGENT);
    } else {
      while (__hip_atomic_load(&g_bar_gen, __ATOMIC_ACQUIRE, __HIP_MEMORY_SCOPE_AGENT) == gen)
        __builtin_amdgcn_s_sleep(2);
    }
    __threadfence();
  }
  __syncthreads();
}

// Partial GEMM: out[n][b] (+n0..n0+63) = sum_{k in [kbase, kbase+NCH*32)} W[n][k] * AT[k][b]
// AT source select: row k -> (k<K0) ? aT0[k][.] : aT1[k-K0][.]
// 256 threads; thread tile 8n x 4b; LDS 26.1 KB.
template<int NCH>
__device__ void gemm_partial(const float* __restrict__ W, int ldw, int n0, int kbase,
                             const float* __restrict__ aT0, const float* __restrict__ aT1, int K0,
                             float* __restrict__ outp, float* lds, int tid)
{
  float (*ws)[72]  = (float (*)[72])lds;            // [32][72]
  float (*hs)[132] = (float (*)[132])(lds + 32*72); // [32][132]
  const int tn = tid>>5, tb = tid&31;
  float acc[8][4];
  #pragma unroll
  for (int j=0;j<8;++j){ acc[j][0]=0.f; acc[j][1]=0.f; acc[j][2]=0.f; acc[j][3]=0.f; }

  for (int c=0;c<NCH;++c){
    const int kb = kbase + c*32;
    { // stage A^T rows kb..kb+31, 16 floats per thread (full 128 b)
      const int kk = tid>>3, q = tid&7;
      const int kg = kb + kk;
      const float* src = ((kg < K0) ? (aT0 + (u64)kg*BSZ) : (aT1 + (u64)(kg-K0)*BSZ)) + q*16;
      float* d = &hs[kk][q*16];
      float4 v0=*(const float4*)(src+0), v1=*(const float4*)(src+4);
      float4 v2=*(const float4*)(src+8), v3=*(const float4*)(src+12);
      *(float4*)(d+0)=v0; *(float4*)(d+4)=v1; *(float4*)(d+8)=v2; *(float4*)(d+12)=v3;
    }
    { // stage W rows n0..n0+63, transposed to ws[k][n]
      const int r = tid>>2, q = tid&3;
      const float* wp = W + (u64)(n0+r)*ldw + kb + q*8;
      float4 w0 = *(const float4*)wp, w1 = *(const float4*)(wp+4);
      ws[q*8+0][r]=w0.x; ws[q*8+1][r]=w0.y; ws[q*8+2][r]=w0.z; ws[q*8+3][r]=w0.w;
      ws[q*8+4][r]=w1.x; ws[q*8+5][r]=w1.y; ws[q*8+6][r]=w1.z; ws[q*8+7][r]=w1.w;
    }
    __syncthreads();
    #pragma unroll 8
    for (int kk=0;kk<32;++kk){
      float4 h4 = *(const float4*)&hs[kk][tb*4];
      float4 wa = *(const float4*)&ws[kk][tn*8];
      float4 wb = *(const float4*)&ws[kk][tn*8+4];
      float wv[8]={wa.x,wa.y,wa.z,wa.w,wb.x,wb.y,wb.z,wb.w};
      float hv[4]={h4.x,h4.y,h4.z,h4.w};
      #pragma unroll
      for (int j=0;j<8;++j){
        #pragma unroll
        for (int i=0;i<4;++i) acc[j][i] += wv[j]*hv[i];
      }
    }
    __syncthreads();
  }
  #pragma unroll
  for (int j=0;j<8;++j){
    float4 o = {acc[j][0],acc[j][1],acc[j][2],acc[j][3]};
    *(float4*)&outp[(u64)(n0 + tn*8 + j)*BSZ + tb*4] = o;
  }
}

#define AM_ENC 0
#define AM_DEC 1
#define AM_CAT 2

// gx[(t*G3+n)*BSZ+b] = A[t,b,:] @ W[n,:]^T + bias[n]; AM_CAT reads [t][k][b] inputs.
template<int AMODE>
__global__ __launch_bounds__(256)
void gemm_gx(const float* __restrict__ embed,
             u64 a1_f, u64 a2_f,
             const int* __restrict__ ids,
             const float* __restrict__ W,
             const float* __restrict__ bias,
             u64 c_f, int K)
{
  constexpr int TM=128, TN=64, TK=32;
  __shared__ float As[TK][TM+4];
  __shared__ float Ws[TK][TN+4];
  __shared__ int rowid[TM];
  const int t = blockIdx.x;
  const int n0 = blockIdx.y*TN;
  const int tid = threadIdx.x;

  if (AMODE != AM_CAT){
    for (int r=tid; r<TM; r+=256)
      rowid[r] = (AMODE==AM_ENC) ? ids[r*TLEN+t] : ((t==0)?1:ids[r*TLEN+t-1]);
    __syncthreads();
  }

  const int tm = tid>>4, tn = tid&15;
  float acc[8][4];
  #pragma unroll
  for (int i=0;i<8;i++){ acc[i][0]=0.f;acc[i][1]=0.f;acc[i][2]=0.f;acc[i][3]=0.f; }

  for (int k0=0;k0<K;k0+=TK){
    if (AMODE==AM_CAT){
      // stage A^T rows k0..k0+31 from [t][k][b] inputs, 16 floats per thread
      const int kk = tid>>3, q = tid&7;
      const int kg = k0 + kk;
      const float* src = g_pool + ((kg<HDIM)? (a1_f + ((u64)t*HDIM + kg)*BSZ)
                                            : (a2_f + ((u64)t*HDIM + (kg-HDIM))*BSZ)) + q*16;
      float* d = &As[kk][q*16];
      float4 v0=*(const float4*)(src+0), v1=*(const float4*)(src+4);
      float4 v2=*(const float4*)(src+8), v3=*(const float4*)(src+12);
      *(float4*)(d+0)=v0; *(float4*)(d+4)=v1; *(float4*)(d+8)=v2; *(float4*)(d+12)=v3;
    } else {
      #pragma unroll
      for (int l=tid; l<TM*TK; l+=256){
        int r=l>>5, k=l&31;
        As[k][r] = embed[(u64)rowid[r]*HDIM + k0 + k];
      }
    }
    #pragma unroll
    for (int l=tid; l<TN*TK; l+=256){
      int n=l>>5, k=l&31;
      Ws[k][n] = W[(u64)(n0+n)*K + k0 + k];
    }
    __syncthreads();
    #pragma unroll 8
    for (int kk=0;kk<TK;kk++){
      float4 a0 = *(const float4*)&As[kk][tm*8];
      float4 a1 = *(const float4*)&As[kk][tm*8+4];
      float4 w  = *(const float4*)&Ws[kk][tn*4];
      float av[8]={a0.x,a0.y,a0.z,a0.w,a1.x,a1.y,a1.z,a1.w};
      float wv[4]={w.x,w.y,w.z,w.w};
      #pragma unroll
      for (int i=0;i<8;i++){
        #pragma unroll
        for (int jj=0;jj<4;jj++) acc[i][jj] += av[i]*wv[jj];
      }
    }
    __syncthreads();
  }

  float bv[4];
  #pragma unroll
  for (int jj=0;jj<4;jj++) bv[jj] = bias[n0+tn*4+jj];
  float* C = g_pool + c_f;
  for (int half=0; half<2; ++half){
    if ((tn>>3)==half){
      #pragma unroll
      for (int i=0;i<8;i++)
        #pragma unroll
        for (int jj=0;jj<4;jj++)
          As[(tn&7)*4+jj][tm*8+i] = acc[i][jj]+bv[jj];
    }
    __syncthreads();
    {
      const int nn = tid>>3, q = tid&7;
      float* dst = C + ((u64)t*G3 + n0 + half*32 + nn)*BSZ + q*16;
      const float* srow = &As[nn][q*16];
      float4 v0=*(const float4*)(srow+0), v1=*(const float4*)(srow+4);
      float4 v2=*(const float4*)(srow+8), v3=*(const float4*)(srow+12);
      *(float4*)(dst+0)=v0; *(float4*)(dst+4)=v1; *(float4*)(dst+8)=v2; *(float4*)(dst+12)=v3;
    }
    __syncthreads();
  }
}

// persistent masked GRU scan; h stored [k][b]; out [t][k][b]
template<bool BWD, bool ACCUM>
__global__ __launch_bounds__(256,2)
void scan_kernel(u64 gx_f, u64 p0_f, u64 p1_f,
                 const float* __restrict__ whh, const float* __restrict__ bhh,
                 const int* __restrict__ lengths, u64 out_f)
{
  __shared__ __align__(16) float lds[6528];
  const int bid = blockIdx.x, tid = threadIdx.x;
  const int j = tid>>6, lane = tid&63;
  const int jg = bid*4 + j;
  const float b_r = bhh[jg], b_z = bhh[HDIM+jg], b_n = bhh[2*HDIM+jg];
  const int lenA = lengths[lane], lenB = lengths[lane+64];

  for (int s=0; s<TLEN; ++s){
    const int t = BWD ? (TLEN-1-s) : s;
    const u64 rd = (s&1)? p0_f : p1_f;
    const u64 wr = (s&1)? p1_f : p0_f;
    if (s>0 && bid<192){
      const int nt = bid>>2, kq = bid&3;
      gemm_partial<8>(whh, HDIM, nt*64, kq*256,
                      g_pool+rd, g_pool+rd, 1<<28,
                      g_pool + F_PART + (u64)kq*G3*BSZ, lds, tid);
    }
    grid_sync();
    #pragma unroll
    for (int h2=0;h2<2;++h2){
      const int b = lane + h2*64;
      const int len = h2 ? lenB : lenA;
      const bool m = (t < len);
      float gr=0.f, gz=0.f, gn=0.f;
      if (s>0){
        #pragma unroll
        for (int q=0;q<4;++q){
          const float* p = g_pool + F_PART + (u64)q*G3*BSZ;
          gr += p[(u64)jg*BSZ + b];
          gz += p[(u64)(HDIM+jg)*BSZ + b];
          gn += p[(u64)(2*HDIM+jg)*BSZ + b];
        }
      }
      const float* gxb = g_pool + gx_f + (u64)t*G3*BSZ;
      const float xr = gxb[(u64)jg*BSZ + b];
      const float xz = gxb[(u64)(HDIM+jg)*BSZ + b];
      const float xn = gxb[(u64)(2*HDIM+jg)*BSZ + b];
      const float hp = (s>0)? g_pool[rd + (u64)jg*BSZ + b] : 0.f;
      const float r = sigmf(xr+gr+b_r);
      const float z = sigmf(xz+gz+b_z);
      const float n = tanhf(xn + r*(gn+b_n));
      const float hv = (1.f-z)*n + z*hp;
      g_pool[wr + (u64)jg*BSZ + b] = m ? hv : hp;
      const u64 oidx = out_f + ((u64)t*HDIM + jg)*BSZ + b;
      if (ACCUM){ if (m) g_pool[oidx] += hv; }
      else g_pool[oidx] = m ? hv : 0.f;
    }
    grid_sync();
  }
}

// persistent decoder: 50 steps x 11 phases
__global__ __launch_bounds__(256,2)
void decoder_kernel(const float* __restrict__ whh0, const float* __restrict__ bhh0,
                    const float* __restrict__ wih1, const float* __restrict__ bih1,
                    const float* __restrict__ whh1, const float* __restrict__ bhh1,
                    const float* __restrict__ cw, const float* __restrict__ cb,
                    const float* __restrict__ ow, const float* __restrict__ ob,
                    const int* __restrict__ tag_ids, const int* __restrict__ lengths,
                    float* __restrict__ dout)
{
  __shared__ __align__(16) float lds[6528];
  const int bid = blockIdx.x, tid = threadIdx.x;
  const int j = tid>>6, lane = tid&63;
  const int jg = bid*4 + j;

  for (int t=0; t<TLEN; ++t){
    const u64 h0c = (t==0)? F_H0F : ((t&1)? F_D0A : F_D0B);
    const u64 h0n = (t&1)? F_D0B : F_D0A;
    const u64 h1c = (t==0)? F_H0B : ((t&1)? F_D1A : F_D1B);
    const u64 h1n = (t&1)? F_D1B : F_D1A;

    // P1g: gh0 partials
    if (bid < 192){
      const int nt = bid>>2, kq = bid&3;
      gemm_partial<8>(whh0, HDIM, nt*64, kq*256,
                      g_pool+h0c, g_pool+h0c, 1<<28,
                      g_pool + F_PART + (u64)kq*G3*BSZ, lds, tid);
    }
    grid_sync();
    // P1p: layer-0 gates
    {
      const float b_r=bhh0[jg], b_z=bhh0[HDIM+jg], b_n=bhh0[2*HDIM+jg];
      #pragma unroll
      for (int h2=0;h2<2;++h2){
        const int b = lane + h2*64;
        float gr=0.f,gz=0.f,gn=0.f;
        #pragma unroll
        for (int q=0;q<4;++q){
          const float* p = g_pool + F_PART + (u64)q*G3*BSZ;
          gr += p[(u64)jg*BSZ+b]; gz += p[(u64)(HDIM+jg)*BSZ+b]; gn += p[(u64)(2*HDIM+jg)*BSZ+b];
        }
        const float* gxb = g_pool + F_GX + (u64)t*G3*BSZ;
        const float xr=gxb[(u64)jg*BSZ+b], xz=gxb[(u64)(HDIM+jg)*BSZ+b], xn=gxb[(u64)(2*HDIM+jg)*BSZ+b];
        const float hp = g_pool[h0c + (u64)jg*BSZ + b];
        const float r = sigmf(xr+gr+b_r), z = sigmf(xz+gz+b_z);
        const float n = tanhf(xn + r*(gn+b_n));
        g_pool[h0n + (u64)jg*BSZ + b] = (1.f-z)*n + z*hp;
      }
    }
    grid_sync();
    // P2g: gxd1 partials (wih1 @ h0new) and gh1 partials (whh1 @ h1prev)
    if (bid < 96){
      const int nt = bid>>1, kq = bid&1;
      gemm_partial<16>(wih1, HDIM, nt*64, kq*512,
                       g_pool+h0n, g_pool+h0n, 1<<28,
                       g_pool + F_PART + (u64)kq*G3*BSZ, lds, tid);
    } else if (bid < 192){
      const int bb = bid-96, nt = bb>>1, kq = bb&1;
      gemm_partial<16>(whh1, HDIM, nt*64, kq*512,
                       g_pool+h1c, g_pool+h1c, 1<<28,
                       g_pool + F_PART + (u64)(2+kq)*G3*BSZ, lds, tid);
    }
    grid_sync();
    // P2p: layer-1 gates
    {
      const float bxr=bih1[jg], bxz=bih1[HDIM+jg], bxn=bih1[2*HDIM+jg];
      const float bhr=bhh1[jg], bhz=bhh1[HDIM+jg], bhn=bhh1[2*HDIM+jg];
      #pragma unroll
      for (int h2=0;h2<2;++h2){
        const int b = lane + h2*64;
        float axr=0.f,axz=0.f,axn=0.f, ahr=0.f,ahz=0.f,ahn=0.f;
        #pragma unroll
        for (int q=0;q<2;++q){
          const float* p = g_pool + F_PART + (u64)q*G3*BSZ;
          axr += p[(u64)jg*BSZ+b]; axz += p[(u64)(HDIM+jg)*BSZ+b]; axn += p[(u64)(2*HDIM+jg)*BSZ+b];
        }
        #pragma unroll
        for (int q=2;q<4;++q){
          const float* p = g_pool + F_PART + (u64)q*G3*BSZ;
          ahr += p[(u64)jg*BSZ+b]; ahz += p[(u64)(HDIM+jg)*BSZ+b]; ahn += p[(u64)(2*HDIM+jg)*BSZ+b];
        }
        const float hp = g_pool[h1c + (u64)jg*BSZ + b];
        const float r = sigmf(axr+bxr+ahr+bhr), z = sigmf(axz+bxz+ahz+bhz);
        const float n = tanhf(axn+bxn + r*(ahn+bhn));
        g_pool[h1n + (u64)jg*BSZ + b] = (1.f-z)*n + z*hp;
      }
    }
    grid_sync();
    // P3: score partials
    if (bid < 100){
      const int tp = bid>>1, kh = bid&1;
      const int b = tid&127, q2 = tid>>7;
      const int kst = kh*512 + q2*256;
      const float* hT = g_pool + h1n;
      const float* eT = g_pool + F_ENC + (u64)tp*HDIM*BSZ;
      float a0=0.f,a1=0.f,a2=0.f,a3=0.f;
      for (int k=kst;k<kst+256;k+=4){
        a0 += hT[(u64)k*BSZ+b]     * eT[(u64)k*BSZ+b];
        a1 += hT[(u64)(k+1)*BSZ+b] * eT[(u64)(k+1)*BSZ+b];
        a2 += hT[(u64)(k+2)*BSZ+b] * eT[(u64)(k+2)*BSZ+b];
        a3 += hT[(u64)(k+3)*BSZ+b] * eT[(u64)(k+3)*BSZ+b];
      }
      g_pool[F_QP + (u64)(kh*2+q2)*TLEN*BSZ + (u64)tp*BSZ + b] = (a0+a1)+(a2+a3);
    }
    grid_sync();
    // P4a: softmax over tp -> attn weights
    if (bid < BSZ && tid < 64){
      const int b = bid;
      float v = -1e30f;
      if (tid < TLEN){
        v = 0.f;
        #pragma unroll
        for (int q=0;q<4;++q) v += g_pool[F_QP + (u64)q*TLEN*BSZ + (u64)tid*BSZ + b];
      }
      float mx = v;
      #pragma unroll
      for (int o=32;o;o>>=1) mx = fmaxf(mx, __shfl_xor(mx,o));
      float e = (tid<TLEN)? __expf(v-mx) : 0.f;
      float sm = e;
      #pragma unroll
      for (int o=32;o;o>>=1) sm += __shfl_xor(sm,o);
      if (tid < TLEN) g_pool[F_A + (u64)tid*BSZ + b] = e/sm;
    }
    grid_sync();
    // P4b: ctx[k][b]
    {
      const int b = tid&127, rh = tid>>7;
      #pragma unroll
      for (int r2=0;r2<2;++r2){
        const int k = bid*4 + rh + 2*r2;
        float acc = 0.f;
        #pragma unroll 5
        for (int tp=0;tp<TLEN;++tp)
          acc += g_pool[F_A + (u64)tp*BSZ + b] * g_pool[F_ENC + ((u64)tp*HDIM + k)*BSZ + b];
        g_pool[F_CTX + (u64)k*BSZ + b] = acc;
      }
    }
    grid_sync();
    // P5g: cc partials, K=2048 concat(h1,ctx)
    if (bid < 128){
      const int nt = bid>>3, kq = bid&7;
      gemm_partial<8>(cw, 2*HDIM, nt*64, kq*256,
                      g_pool+h1n, g_pool+F_CTX, HDIM,
                      g_pool + F_PART + (u64)kq*HDIM*BSZ, lds, tid);
    }
    grid_sync();
    // P5p: cc = tanh(sum + cb)
    {
      #pragma unroll
      for (int h2=0;h2<2;++h2){
        const int b = lane + h2*64;
        float a = cb[jg];
        #pragma unroll
        for (int q=0;q<8;++q) a += g_pool[F_PART + (u64)q*HDIM*BSZ + (u64)jg*BSZ + b];
        g_pool[F_CC + (u64)jg*BSZ + b] = tanhf(a);
      }
    }
    grid_sync();
    // P6a: logits partials
    if (bid < 16){
      const int nt = bid>>2, kq = bid&3;
      gemm_partial<8>(ow, HDIM, nt*64, kq*256,
                      g_pool+F_CC, g_pool+F_CC, 1<<28,
                      g_pool + F_P6 + (u64)kq*NTAG*BSZ, lds, tid);
    }
    grid_sync();
    // P6b: sum partials, softmax per b, write dout + nll
    if (bid < BSZ){
      float* lgs = lds; float* red = lds + 256;
      const int b = bid, v = tid;
      float lg = ob[v];
      #pragma unroll
      for (int q=0;q<4;++q) lg += g_pool[F_P6 + (u64)q*NTAG*BSZ + (u64)v*BSZ + b];
      lgs[v] = lg; red[v] = lg;
      __syncthreads();
      for (int o=128;o;o>>=1){ if (tid<o) red[tid]=fmaxf(red[tid],red[tid+o]); __syncthreads(); }
      const float mx = red[0];
      __syncthreads();
      red[tid] = __expf(lg-mx);
      __syncthreads();
      for (int o=128;o;o>>=1){ if (tid<o) red[tid]+=red[tid+o]; __syncthreads(); }
      const float lse = mx + __logf(red[0]);
      dout[((u64)b*TLEN + t)*NTAG + v] = lg;
      if (tid==0){
        const int tag = tag_ids[b*TLEN + t];
        g_pool[F_NLL + (u64)t*BSZ + b] = lse - lgs[tag];
      }
    }
    // no barrier needed: next P1g touches only F_PART/h (disjoint from P6b)
  }
  grid_sync();
  // loss
  if (bid == 0){
    float ssum = 0.f;
    for (int i=tid; i<TLEN*BSZ; i+=256){
      const int tt = i>>7, b = i&127;
      if (tt < lengths[b]) ssum += g_pool[F_NLL + i];
    }
    lds[tid] = ssum; __syncthreads();
    for (int o=128;o;o>>=1){ if (tid<o) lds[tid]+=lds[tid+o]; __syncthreads(); }
    if (tid==0){
      int den=0;
      for (int b=0;b<BSZ;b++) den += lengths[b];
      dout[(u64)BSZ*TLEN*NTAG] = lds[0]/(float)den;
    }
  }
}

extern "C" void kernel_launch(void* const* d_in, const int* in_sizes, int n_in,
                              void* d_out, int out_size, void* d_ws, size_t ws_size,
                              hipStream_t stream)
{
  const float* enc_embed = (const float*)d_in[0];
  const float* e0_wih = (const float*)d_in[1];
  const float* e0_whh = (const float*)d_in[2];
  const float* e0_bih = (const float*)d_in[3];
  const float* e0_bhh = (const float*)d_in[4];
  const float* e1_wih = (const float*)d_in[5];
  const float* e1_whh = (const float*)d_in[6];
  const float* e1_bih = (const float*)d_in[7];
  const float* e1_bhh = (const float*)d_in[8];
  const float* dec_embed = (const float*)d_in[9];
  const float* d_wih = (const float*)d_in[10];
  const float* d_whh = (const float*)d_in[11];
  const float* d_bih = (const float*)d_in[12];
  const float* d_bhh = (const float*)d_in[13];
  const float* concat_w = (const float*)d_in[14];
  const float* concat_b = (const float*)d_in[15];
  const float* out_w = (const float*)d_in[16];
  const float* out_b = (const float*)d_in[17];
  const int* input_ids = (const int*)d_in[18];
  const int* tag_ids  = (const int*)d_in[19];
  const int* lengths  = (const int*)d_in[20];
  float* dout = (float*)d_out;

  const dim3 gxg(TLEN, G3/64);

  // encoder L0 fwd
  gemm_gx<AM_ENC><<<gxg,256,0,stream>>>(enc_embed,0,0,input_ids,e0_wih,e0_bih,F_GX,HDIM);
  scan_kernel<false,false><<<NBLK,256,0,stream>>>(F_GX, F_T0, F_H0F, e0_whh, e0_bhh, lengths, F_OF0);
  // encoder L0 bwd
  gemm_gx<AM_ENC><<<gxg,256,0,stream>>>(enc_embed,0,0,input_ids,
                                        e0_wih+(u64)G3*HDIM, e0_bih+G3, F_GX, HDIM);
  scan_kernel<true,false><<<NBLK,256,0,stream>>>(F_GX, F_T0, F_H0B,
                                        e0_whh+(u64)G3*HDIM, e0_bhh+G3, lengths, F_OB0);
  // encoder L1 fwd
  gemm_gx<AM_CAT><<<gxg,256,0,stream>>>(nullptr, F_OF0, F_OB0, nullptr,
                                        e1_wih, e1_bih, F_GX, 2*HDIM);
  scan_kernel<false,false><<<NBLK,256,0,stream>>>(F_GX, F_T0, F_T1, e1_whh, e1_bhh, lengths, F_ENC);
  // encoder L1 bwd (accumulate)
  gemm_gx<AM_CAT><<<gxg,256,0,stream>>>(nullptr, F_OF0, F_OB0, nullptr,
                                        e1_wih+(u64)G3*2*HDIM, e1_bih+G3, F_GX, 2*HDIM);
  scan_kernel<true,true><<<NBLK,256,0,stream>>>(F_GX, F_T0, F_T1,
                                        e1_whh+(u64)G3*HDIM, e1_bhh+G3, lengths, F_ENC);
  // decoder
  gemm_gx<AM_DEC><<<gxg,256,0,stream>>>(dec_embed,0,0,tag_ids, d_wih, d_bih, F_GX, HDIM);
  decoder_kernel<<<NBLK,256,0,stream>>>(d_whh, d_bhh,
                                        d_wih+(u64)G3*HDIM, d_bih+G3,
                                        d_whh+(u64)G3*HDIM, d_bhh+G3,
                                        concat_w, concat_b, out_w, out_b,
                                        tag_ids, lengths, dout);
}

// Round 8
// 49811.270 us; speedup vs baseline: 1.8980x; 1.2195x over previous
//
#include <hip/hip_runtime.h>
#include <math.h>

#define HDIM 1024
#define NTAG 256
#define BSZ 128
#define TLEN 50
#define G3 3072
#define NBLK 256

typedef unsigned long long u64;

// ---- static f32 pool, recurrent tensors transposed [k][b] ----
constexpr u64 GX_F  = (u64)TLEN*G3*BSZ;     // gx [t][n][b]
constexpr u64 SEQ_F = (u64)TLEN*HDIM*BSZ;   // [t][k][b]
constexpr u64 HST_F = (u64)HDIM*BSZ;        // h [k][b]
constexpr u64 F_GX  = 0;
constexpr u64 F_OF0 = F_GX + GX_F;
constexpr u64 F_OB0 = F_OF0 + SEQ_F;
constexpr u64 F_ENC = F_OB0 + SEQ_F;
constexpr u64 F_T0  = F_ENC + SEQ_F;
constexpr u64 F_T1  = F_T0 + HST_F;
constexpr u64 F_H0F = F_T1 + HST_F;
constexpr u64 F_H0B = F_H0F + HST_F;
constexpr u64 F_D0A = F_H0B + HST_F;
constexpr u64 F_D0B = F_D0A + HST_F;
constexpr u64 F_D1A = F_D0B + HST_F;
constexpr u64 F_D1B = F_D1A + HST_F;
constexpr u64 F_CTX = F_D1B + HST_F;
constexpr u64 F_CC  = F_CTX + HST_F;
constexpr u64 F_PART= F_CC + HST_F;                 // 8 x G3 x BSZ partial pool
constexpr u64 F_P6  = F_PART + (u64)8*G3*BSZ;       // 8 x NTAG x BSZ logits partials
constexpr u64 F_QP  = F_P6 + (u64)8*NTAG*BSZ;       // 4 x TLEN x BSZ score partials
constexpr u64 F_A   = F_QP + (u64)4*TLEN*BSZ;       // attn weights [tp][b]
constexpr u64 F_NLL = F_A + (u64)TLEN*BSZ;
constexpr u64 POOL_F= F_NLL + (u64)TLEN*BSZ;

__device__ __align__(256) float g_pool[POOL_F];
__device__ unsigned g_bar_cnt = 0;
__device__ unsigned g_bar_gen = 0;

__device__ __forceinline__ float sigmf(float x){ return 1.f/(1.f+__expf(-x)); }

// software grid barrier; grid==256 blocks, all co-resident (1/CU)
__device__ __forceinline__ void grid_sync(){
  __syncthreads();
  if (threadIdx.x == 0){
    __threadfence();
    unsigned gen = __hip_atomic_load(&g_bar_gen, __ATOMIC_RELAXED, __HIP_MEMORY_SCOPE_AGENT);
    unsigned old = __hip_atomic_fetch_add(&g_bar_cnt, 1u, __ATOMIC_ACQ_REL, __HIP_MEMORY_SCOPE_AGENT);
    if (old == (unsigned)(NBLK-1)){
      __hip_atomic_store(&g_bar_cnt, 0u, __ATOMIC_RELAXED, __HIP_MEMORY_SCOPE_AGENT);
      __hip_atomic_fetch_add(&g_bar_gen, 1u, __ATOMIC_ACQ_REL, __HIP_MEMORY_SCOPE_AGENT);
    } else {
      while (__hip_atomic_load(&g_bar_gen, __ATOMIC_ACQUIRE, __HIP_MEMORY_SCOPE_AGENT) == gen)
        __builtin_amdgcn_s_sleep(2);
    }
    __threadfence();
  }
  __syncthreads();
}

// Resident partial GEMM: W slice (48n x 256k) already in LDS wl[k][n].
// out[n0+n][b] = sum_{k in [kbase,kbase+256)} W[n][k] * AT[k][b]
// thread tile 12n x 2b (tn=tid>>6 in 0..3 wave-uniform, tb=tid&63)
__device__ void gemm_res(const float* __restrict__ wl,
                         const float* __restrict__ aT0, const float* __restrict__ aT1, int K0,
                         int kbase, float (*hs)[132], int n0,
                         float* __restrict__ outp, int tid)
{
  const int tn = tid>>6, tb = tid&63;
  float acc[12][2];
  #pragma unroll
  for (int j=0;j<12;++j){ acc[j][0]=0.f; acc[j][1]=0.f; }
  for (int c=0;c<16;++c){
    const int kb = kbase + c*16;
    { // stage A 16k x 128b, 8 floats/thread
      const int kk = tid>>4, q = tid&15;
      const int kg = kb + kk;
      const float* src = ((kg<K0)? (aT0 + (u64)kg*BSZ) : (aT1 + (u64)(kg-K0)*BSZ)) + q*8;
      float4 v0 = *(const float4*)src, v1 = *(const float4*)(src+4);
      *(float4*)&hs[kk][q*8] = v0; *(float4*)&hs[kk][q*8+4] = v1;
    }
    __syncthreads();
    #pragma unroll
    for (int kk=0;kk<16;++kk){
      const float* wrow = wl + (u64)(c*16+kk)*48 + tn*12;
      float4 w0 = *(const float4*)(wrow);
      float4 w1 = *(const float4*)(wrow+4);
      float4 w2 = *(const float4*)(wrow+8);
      float2 a = *(const float2*)&hs[kk][tb*2];
      float wv[12] = {w0.x,w0.y,w0.z,w0.w,w1.x,w1.y,w1.z,w1.w,w2.x,w2.y,w2.z,w2.w};
      #pragma unroll
      for (int j=0;j<12;++j){ acc[j][0] += wv[j]*a.x; acc[j][1] += wv[j]*a.y; }
    }
    __syncthreads();
  }
  #pragma unroll
  for (int j=0;j<12;++j){
    float2 o = {acc[j][0], acc[j][1]};
    *(float2*)&outp[(u64)(n0 + tn*12 + j)*BSZ + tb*2] = o;
  }
}

// Streaming partial GEMM (for cw/ow; per-block W slice is L2-resident across steps).
// NPT=8 -> 64-wide n tile; NPT=4 -> 32-wide. thread tile NPT n x 4 b.
template<int NPT>
__device__ void gemm_stream(const float* __restrict__ W, int ldw, int n0, int kbase, int nch,
                            const float* __restrict__ aT0, const float* __restrict__ aT1, int K0,
                            float (*hs)[132], float (*ws)[68],
                            float* __restrict__ outp, int tid)
{
  const int tn = tid>>5, tb = tid&31;
  float acc[NPT][4];
  #pragma unroll
  for (int j=0;j<NPT;++j){ acc[j][0]=0.f;acc[j][1]=0.f;acc[j][2]=0.f;acc[j][3]=0.f; }
  for (int c=0;c<nch;++c){
    const int kb = kbase + c*16;
    {
      const int kk = tid>>4, q = tid&15;
      const int kg = kb + kk;
      const float* src = ((kg<K0)? (aT0 + (u64)kg*BSZ) : (aT1 + (u64)(kg-K0)*BSZ)) + q*8;
      float4 v0 = *(const float4*)src, v1 = *(const float4*)(src+4);
      *(float4*)&hs[kk][q*8] = v0; *(float4*)&hs[kk][q*8+4] = v1;
    }
    if (NPT==8){ // 64n x 16k, 4 floats/thread
      const int n = tid>>2, kg4 = tid&3;
      float4 w = *(const float4*)&W[(u64)(n0+n)*ldw + kb + kg4*4];
      ws[kg4*4+0][n]=w.x; ws[kg4*4+1][n]=w.y; ws[kg4*4+2][n]=w.z; ws[kg4*4+3][n]=w.w;
    } else {     // 32n x 16k, 2 floats/thread
      const int n = tid>>3, kg2 = tid&7;
      float2 w = *(const float2*)&W[(u64)(n0+n)*ldw + kb + kg2*2];
      ws[kg2*2+0][n]=w.x; ws[kg2*2+1][n]=w.y;
    }
    __syncthreads();
    #pragma unroll
    for (int kk=0;kk<16;++kk){
      float4 a = *(const float4*)&hs[kk][tb*4];
      float wv[NPT];
      if (NPT==8){
        float4 wa = *(const float4*)&ws[kk][tn*8];
        float4 wb = *(const float4*)&ws[kk][tn*8+4];
        wv[0]=wa.x;wv[1]=wa.y;wv[2]=wa.z;wv[3]=wa.w;wv[4]=wb.x;wv[5]=wb.y;wv[6]=wb.z;wv[7]=wb.w;
      } else {
        float4 wa = *(const float4*)&ws[kk][tn*4];
        wv[0]=wa.x;wv[1]=wa.y;wv[2]=wa.z;wv[3]=wa.w;
      }
      #pragma unroll
      for (int j=0;j<NPT;++j){
        acc[j][0]+=wv[j]*a.x; acc[j][1]+=wv[j]*a.y; acc[j][2]+=wv[j]*a.z; acc[j][3]+=wv[j]*a.w;
      }
    }
    __syncthreads();
  }
  #pragma unroll
  for (int j=0;j<NPT;++j){
    float4 o={acc[j][0],acc[j][1],acc[j][2],acc[j][3]};
    *(float4*)&outp[(u64)(n0+tn*NPT+j)*BSZ + tb*4] = o;
  }
}

#define AM_ENC 0
#define AM_DEC 1
#define AM_CAT 2

// gx[(t*G3+n)*BSZ+b] = A[t,b,:] @ W[n,:]^T + bias[n]  (unchanged from round 7)
template<int AMODE>
__global__ __launch_bounds__(256)
void gemm_gx(const float* __restrict__ embed,
             u64 a1_f, u64 a2_f,
             const int* __restrict__ ids,
             const float* __restrict__ W,
             const float* __restrict__ bias,
             u64 c_f, int K)
{
  constexpr int TM=128, TN=64, TK=32;
  __shared__ float As[TK][TM+4];
  __shared__ float Ws[TK][TN+4];
  __shared__ int rowid[TM];
  const int t = blockIdx.x;
  const int n0 = blockIdx.y*TN;
  const int tid = threadIdx.x;

  if (AMODE != AM_CAT){
    for (int r=tid; r<TM; r+=256)
      rowid[r] = (AMODE==AM_ENC) ? ids[r*TLEN+t] : ((t==0)?1:ids[r*TLEN+t-1]);
    __syncthreads();
  }

  const int tm = tid>>4, tn = tid&15;
  float acc[8][4];
  #pragma unroll
  for (int i=0;i<8;i++){ acc[i][0]=0.f;acc[i][1]=0.f;acc[i][2]=0.f;acc[i][3]=0.f; }

  for (int k0=0;k0<K;k0+=TK){
    if (AMODE==AM_CAT){
      const int kk = tid>>3, q = tid&7;
      const int kg = k0 + kk;
      const float* src = g_pool + ((kg<HDIM)? (a1_f + ((u64)t*HDIM + kg)*BSZ)
                                            : (a2_f + ((u64)t*HDIM + (kg-HDIM))*BSZ)) + q*16;
      float* d = &As[kk][q*16];
      float4 v0=*(const float4*)(src+0), v1=*(const float4*)(src+4);
      float4 v2=*(const float4*)(src+8), v3=*(const float4*)(src+12);
      *(float4*)(d+0)=v0; *(float4*)(d+4)=v1; *(float4*)(d+8)=v2; *(float4*)(d+12)=v3;
    } else {
      #pragma unroll
      for (int l=tid; l<TM*TK; l+=256){
        int r=l>>5, k=l&31;
        As[k][r] = embed[(u64)rowid[r]*HDIM + k0 + k];
      }
    }
    #pragma unroll
    for (int l=tid; l<TN*TK; l+=256){
      int n=l>>5, k=l&31;
      Ws[k][n] = W[(u64)(n0+n)*K + k0 + k];
    }
    __syncthreads();
    #pragma unroll 8
    for (int kk=0;kk<TK;kk++){
      float4 a0 = *(const float4*)&As[kk][tm*8];
      float4 a1 = *(const float4*)&As[kk][tm*8+4];
      float4 w  = *(const float4*)&Ws[kk][tn*4];
      float av[8]={a0.x,a0.y,a0.z,a0.w,a1.x,a1.y,a1.z,a1.w};
      float wv[4]={w.x,w.y,w.z,w.w};
      #pragma unroll
      for (int i=0;i<8;i++){
        #pragma unroll
        for (int jj=0;jj<4;jj++) acc[i][jj] += av[i]*wv[jj];
      }
    }
    __syncthreads();
  }

  float bv[4];
  #pragma unroll
  for (int jj=0;jj<4;jj++) bv[jj] = bias[n0+tn*4+jj];
  float* C = g_pool + c_f;
  for (int half=0; half<2; ++half){
    if ((tn>>3)==half){
      #pragma unroll
      for (int i=0;i<8;i++)
        #pragma unroll
        for (int jj=0;jj<4;jj++)
          As[(tn&7)*4+jj][tm*8+i] = acc[i][jj]+bv[jj];
    }
    __syncthreads();
    {
      const int nn = tid>>3, q = tid&7;
      float* dst = C + ((u64)t*G3 + n0 + half*32 + nn)*BSZ + q*16;
      const float* srow = &As[nn][q*16];
      float4 v0=*(const float4*)(srow+0), v1=*(const float4*)(srow+4);
      float4 v2=*(const float4*)(srow+8), v3=*(const float4*)(srow+12);
      *(float4*)(dst+0)=v0; *(float4*)(dst+4)=v1; *(float4*)(dst+8)=v2; *(float4*)(dst+12)=v3;
    }
    __syncthreads();
  }
}

// persistent masked GRU scan, whh slice LDS-resident across 50 steps
template<bool BWD, bool ACCUM>
__global__ __launch_bounds__(256)
void scan_kernel(u64 gx_f, u64 p0_f, u64 p1_f,
                 const float* __restrict__ whh, const float* __restrict__ bhh,
                 const int* __restrict__ lengths, u64 out_f)
{
  __shared__ float wl[256*48];
  __shared__ __align__(16) float hs[16][132];
  const int bid = blockIdx.x, tid = threadIdx.x;
  const int nt = bid>>2, kq = bid&3;
  const int n0 = nt*48, kbase = kq*256;
  // preload W slice: wl[k][n] = whh[n0+n][kbase+k]
  for (int m=0;m<48;++m)
    wl[(u64)tid*48 + m] = whh[(u64)(n0+m)*HDIM + kbase + tid];
  __syncthreads();

  const int j = tid>>6, lane = tid&63;
  const int jg = bid*4 + j;
  const float b_r = bhh[jg], b_z = bhh[HDIM+jg], b_n = bhh[2*HDIM+jg];
  const int lenA = lengths[lane], lenB = lengths[lane+64];

  for (int s=0; s<TLEN; ++s){
    const int t = BWD ? (TLEN-1-s) : s;
    const u64 rd = (s&1)? p0_f : p1_f;
    const u64 wr = (s&1)? p1_f : p0_f;
    if (s>0){
      gemm_res(wl, g_pool+rd, g_pool+rd, 1<<28, kbase, hs, n0,
               g_pool + F_PART + (u64)kq*G3*BSZ, tid);
    }
    grid_sync();
    #pragma unroll
    for (int h2=0;h2<2;++h2){
      const int b = lane + h2*64;
      const int len = h2 ? lenB : lenA;
      const bool m = (t < len);
      float gr=0.f, gz=0.f, gn=0.f;
      if (s>0){
        #pragma unroll
        for (int q=0;q<4;++q){
          const float* p = g_pool + F_PART + (u64)q*G3*BSZ;
          gr += p[(u64)jg*BSZ + b];
          gz += p[(u64)(HDIM+jg)*BSZ + b];
          gn += p[(u64)(2*HDIM+jg)*BSZ + b];
        }
      }
      const float* gxb = g_pool + gx_f + (u64)t*G3*BSZ;
      const float xr = gxb[(u64)jg*BSZ + b];
      const float xz = gxb[(u64)(HDIM+jg)*BSZ + b];
      const float xn = gxb[(u64)(2*HDIM+jg)*BSZ + b];
      const float hp = (s>0)? g_pool[rd + (u64)jg*BSZ + b] : 0.f;
      const float r = sigmf(xr+gr+b_r);
      const float z = sigmf(xz+gz+b_z);
      const float n = tanhf(xn + r*(gn+b_n));
      const float hv = (1.f-z)*n + z*hp;
      g_pool[wr + (u64)jg*BSZ + b] = m ? hv : hp;
      const u64 oidx = out_f + ((u64)t*HDIM + jg)*BSZ + b;
      if (ACCUM){ if (m) g_pool[oidx] += hv; }
      else g_pool[oidx] = m ? hv : 0.f;
    }
    grid_sync();
  }
}

// persistent decoder, whh0/wih1/whh1 LDS-resident; cw/ow streamed (L2-resident slices)
__global__ __launch_bounds__(256)
void decoder_kernel(const float* __restrict__ whh0, const float* __restrict__ bhh0,
                    const float* __restrict__ wih1, const float* __restrict__ bih1,
                    const float* __restrict__ whh1, const float* __restrict__ bhh1,
                    const float* __restrict__ cw, const float* __restrict__ cb,
                    const float* __restrict__ ow, const float* __restrict__ ob,
                    const int* __restrict__ tag_ids, const int* __restrict__ lengths,
                    float* __restrict__ dout)
{
  __shared__ float wl0[256*48];
  __shared__ float wl1[256*48];
  __shared__ float wl2[256*48];
  __shared__ __align__(16) float hs[16][132];
  __shared__ __align__(16) float ws[16][68];
  const int bid = blockIdx.x, tid = threadIdx.x;
  const int nt = bid>>2, kq = bid&3;
  const int n0 = nt*48, kbase = kq*256;
  // preload the three recurrent weight slices
  for (int m=0;m<48;++m){
    wl0[(u64)tid*48 + m] = whh0[(u64)(n0+m)*HDIM + kbase + tid];
    wl1[(u64)tid*48 + m] = wih1[(u64)(n0+m)*HDIM + kbase + tid];
    wl2[(u64)tid*48 + m] = whh1[(u64)(n0+m)*HDIM + kbase + tid];
  }
  __syncthreads();

  const int j = tid>>6, lane = tid&63;
  const int jg = bid*4 + j;

  for (int t=0; t<TLEN; ++t){
    const u64 h0c = (t==0)? F_H0F : ((t&1)? F_D0A : F_D0B);
    const u64 h0n = (t&1)? F_D0B : F_D0A;
    const u64 h1c = (t==0)? F_H0B : ((t&1)? F_D1A : F_D1B);
    const u64 h1n = (t&1)? F_D1B : F_D1A;

    // P1g: gh0 partials (whh0 @ h0c), slots 0..3
    gemm_res(wl0, g_pool+h0c, g_pool+h0c, 1<<28, kbase, hs, n0,
             g_pool + F_PART + (u64)kq*G3*BSZ, tid);
    grid_sync();
    // P1p: layer-0 gates
    {
      const float b_r=bhh0[jg], b_z=bhh0[HDIM+jg], b_n=bhh0[2*HDIM+jg];
      #pragma unroll
      for (int h2=0;h2<2;++h2){
        const int b = lane + h2*64;
        float gr=0.f,gz=0.f,gn=0.f;
        #pragma unroll
        for (int q=0;q<4;++q){
          const float* p = g_pool + F_PART + (u64)q*G3*BSZ;
          gr += p[(u64)jg*BSZ+b]; gz += p[(u64)(HDIM+jg)*BSZ+b]; gn += p[(u64)(2*HDIM+jg)*BSZ+b];
        }
        const float* gxb = g_pool + F_GX + (u64)t*G3*BSZ;
        const float xr=gxb[(u64)jg*BSZ+b], xz=gxb[(u64)(HDIM+jg)*BSZ+b], xn=gxb[(u64)(2*HDIM+jg)*BSZ+b];
        const float hp = g_pool[h0c + (u64)jg*BSZ + b];
        const float r = sigmf(xr+gr+b_r), z = sigmf(xz+gz+b_z);
        const float n = tanhf(xn + r*(gn+b_n));
        g_pool[h0n + (u64)jg*BSZ + b] = (1.f-z)*n + z*hp;
      }
    }
    grid_sync();
    // P2g: wih1@h0n -> slots 0..3 ; whh1@h1c -> slots 4..7
    gemm_res(wl1, g_pool+h0n, g_pool+h0n, 1<<28, kbase, hs, n0,
             g_pool + F_PART + (u64)kq*G3*BSZ, tid);
    gemm_res(wl2, g_pool+h1c, g_pool+h1c, 1<<28, kbase, hs, n0,
             g_pool + F_PART + (u64)(4+kq)*G3*BSZ, tid);
    grid_sync();
    // P2p: layer-1 gates
    {
      const float bxr=bih1[jg], bxz=bih1[HDIM+jg], bxn=bih1[2*HDIM+jg];
      const float bhr=bhh1[jg], bhz=bhh1[HDIM+jg], bhn=bhh1[2*HDIM+jg];
      #pragma unroll
      for (int h2=0;h2<2;++h2){
        const int b = lane + h2*64;
        float axr=0.f,axz=0.f,axn=0.f, ahr=0.f,ahz=0.f,ahn=0.f;
        #pragma unroll
        for (int q=0;q<4;++q){
          const float* p = g_pool + F_PART + (u64)q*G3*BSZ;
          axr += p[(u64)jg*BSZ+b]; axz += p[(u64)(HDIM+jg)*BSZ+b]; axn += p[(u64)(2*HDIM+jg)*BSZ+b];
        }
        #pragma unroll
        for (int q=4;q<8;++q){
          const float* p = g_pool + F_PART + (u64)q*G3*BSZ;
          ahr += p[(u64)jg*BSZ+b]; ahz += p[(u64)(HDIM+jg)*BSZ+b]; ahn += p[(u64)(2*HDIM+jg)*BSZ+b];
        }
        const float hp = g_pool[h1c + (u64)jg*BSZ + b];
        const float r = sigmf(axr+bxr+ahr+bhr), z = sigmf(axz+bxz+ahz+bhz);
        const float n = tanhf(axn+bxn + r*(ahn+bhn));
        g_pool[h1n + (u64)jg*BSZ + b] = (1.f-z)*n + z*hp;
      }
    }
    grid_sync();
    // P3: score partials
    if (bid < 100){
      const int tp = bid>>1, kh = bid&1;
      const int b = tid&127, q2 = tid>>7;
      const int kst = kh*512 + q2*256;
      const float* hT = g_pool + h1n;
      const float* eT = g_pool + F_ENC + (u64)tp*HDIM*BSZ;
      float a0=0.f,a1=0.f,a2=0.f,a3=0.f;
      for (int k=kst;k<kst+256;k+=4){
        a0 += hT[(u64)k*BSZ+b]     * eT[(u64)k*BSZ+b];
        a1 += hT[(u64)(k+1)*BSZ+b] * eT[(u64)(k+1)*BSZ+b];
        a2 += hT[(u64)(k+2)*BSZ+b] * eT[(u64)(k+2)*BSZ+b];
        a3 += hT[(u64)(k+3)*BSZ+b] * eT[(u64)(k+3)*BSZ+b];
      }
      g_pool[F_QP + (u64)(kh*2+q2)*TLEN*BSZ + (u64)tp*BSZ + b] = (a0+a1)+(a2+a3);
    }
    grid_sync();
    // P4a: softmax over tp
    if (bid < BSZ && tid < 64){
      const int b = bid;
      float v = -1e30f;
      if (tid < TLEN){
        v = 0.f;
        #pragma unroll
        for (int q=0;q<4;++q) v += g_pool[F_QP + (u64)q*TLEN*BSZ + (u64)tid*BSZ + b];
      }
      float mx = v;
      #pragma unroll
      for (int o=32;o;o>>=1) mx = fmaxf(mx, __shfl_xor(mx,o));
      float e = (tid<TLEN)? __expf(v-mx) : 0.f;
      float sm = e;
      #pragma unroll
      for (int o=32;o;o>>=1) sm += __shfl_xor(sm,o);
      if (tid < TLEN) g_pool[F_A + (u64)tid*BSZ + b] = e/sm;
    }
    grid_sync();
    // P4b: ctx[k][b]
    {
      const int b = tid&127, rh = tid>>7;
      #pragma unroll
      for (int r2=0;r2<2;++r2){
        const int k = bid*4 + rh + 2*r2;
        float acc = 0.f;
        #pragma unroll 5
        for (int tp=0;tp<TLEN;++tp)
          acc += g_pool[F_A + (u64)tp*BSZ + b] * g_pool[F_ENC + ((u64)tp*HDIM + k)*BSZ + b];
        g_pool[F_CTX + (u64)k*BSZ + b] = acc;
      }
    }
    grid_sync();
    // P5g: cc partials over K=2048 concat(h1n,ctx): 256 blocks (16 n-tiles x 16 k-chunks)
    {
      const int nt5 = bid>>4, kq5 = bid&15;
      gemm_stream<8>(cw, 2*HDIM, nt5*64, kq5*128, 8,
                     g_pool+h1n, g_pool+F_CTX, HDIM,
                     hs, ws, g_pool + F_PART + (u64)kq5*HDIM*BSZ, tid);
    }
    grid_sync();
    // P5p: cc = tanh(sum16 + cb)
    {
      #pragma unroll
      for (int h2=0;h2<2;++h2){
        const int b = lane + h2*64;
        float a = cb[jg];
        #pragma unroll
        for (int q=0;q<16;++q) a += g_pool[F_PART + (u64)q*HDIM*BSZ + (u64)jg*BSZ + b];
        g_pool[F_CC + (u64)jg*BSZ + b] = tanhf(a);
      }
    }
    grid_sync();
    // P6a: logits partials: 64 blocks (8 n-tiles of 32 x 8 k-chunks)
    if (bid < 64){
      const int nt6 = bid>>3, kq6 = bid&7;
      gemm_stream<4>(ow, HDIM, nt6*32, kq6*128, 8,
                     g_pool+F_CC, g_pool+F_CC, 1<<28,
                     hs, ws, g_pool + F_P6 + (u64)kq6*NTAG*BSZ, tid);
    }
    grid_sync();
    // P6b: sum partials, per-b softmax, write dout + nll
    if (bid < BSZ){
      float* lgs = (float*)hs; float* red = ((float*)hs) + 256;
      const int b = bid, v = tid;
      float lg = ob[v];
      #pragma unroll
      for (int q=0;q<8;++q) lg += g_pool[F_P6 + (u64)q*NTAG*BSZ + (u64)v*BSZ + b];
      lgs[v] = lg; red[v] = lg;
      __syncthreads();
      for (int o=128;o;o>>=1){ if (tid<o) red[tid]=fmaxf(red[tid],red[tid+o]); __syncthreads(); }
      const float mx = red[0];
      __syncthreads();
      red[tid] = __expf(lg-mx);
      __syncthreads();
      for (int o=128;o;o>>=1){ if (tid<o) red[tid]+=red[tid+o]; __syncthreads(); }
      const float lse = mx + __logf(red[0]);
      dout[((u64)b*TLEN + t)*NTAG + v] = lg;
      if (tid==0){
        const int tag = tag_ids[b*TLEN + t];
        g_pool[F_NLL + (u64)t*BSZ + b] = lse - lgs[tag];
      }
    }
    // no barrier needed before next P1g (disjoint buffers)
  }
  grid_sync();
  // loss
  if (bid == 0){
    float* red = (float*)hs;
    float ssum = 0.f;
    for (int i=tid; i<TLEN*BSZ; i+=256){
      const int tt = i>>7, b = i&127;
      if (tt < lengths[b]) ssum += g_pool[F_NLL + i];
    }
    red[tid] = ssum; __syncthreads();
    for (int o=128;o;o>>=1){ if (tid<o) red[tid]+=red[tid+o]; __syncthreads(); }
    if (tid==0){
      int den=0;
      for (int b=0;b<BSZ;b++) den += lengths[b];
      dout[(u64)BSZ*TLEN*NTAG] = red[0]/(float)den;
    }
  }
}

extern "C" void kernel_launch(void* const* d_in, const int* in_sizes, int n_in,
                              void* d_out, int out_size, void* d_ws, size_t ws_size,
                              hipStream_t stream)
{
  const float* enc_embed = (const float*)d_in[0];
  const float* e0_wih = (const float*)d_in[1];
  const float* e0_whh = (const float*)d_in[2];
  const float* e0_bih = (const float*)d_in[3];
  const float* e0_bhh = (const float*)d_in[4];
  const float* e1_wih = (const float*)d_in[5];
  const float* e1_whh = (const float*)d_in[6];
  const float* e1_bih = (const float*)d_in[7];
  const float* e1_bhh = (const float*)d_in[8];
  const float* dec_embed = (const float*)d_in[9];
  const float* d_wih = (const float*)d_in[10];
  const float* d_whh = (const float*)d_in[11];
  const float* d_bih = (const float*)d_in[12];
  const float* d_bhh = (const float*)d_in[13];
  const float* concat_w = (const float*)d_in[14];
  const float* concat_b = (const float*)d_in[15];
  const float* out_w = (const float*)d_in[16];
  const float* out_b = (const float*)d_in[17];
  const int* input_ids = (const int*)d_in[18];
  const int* tag_ids  = (const int*)d_in[19];
  const int* lengths  = (const int*)d_in[20];
  float* dout = (float*)d_out;

  const dim3 gxg(TLEN, G3/64);

  // encoder L0 fwd
  gemm_gx<AM_ENC><<<gxg,256,0,stream>>>(enc_embed,0,0,input_ids,e0_wih,e0_bih,F_GX,HDIM);
  scan_kernel<false,false><<<NBLK,256,0,stream>>>(F_GX, F_T0, F_H0F, e0_whh, e0_bhh, lengths, F_OF0);
  // encoder L0 bwd
  gemm_gx<AM_ENC><<<gxg,256,0,stream>>>(enc_embed,0,0,input_ids,
                                        e0_wih+(u64)G3*HDIM, e0_bih+G3, F_GX, HDIM);
  scan_kernel<true,false><<<NBLK,256,0,stream>>>(F_GX, F_T0, F_H0B,
                                        e0_whh+(u64)G3*HDIM, e0_bhh+G3, lengths, F_OB0);
  // encoder L1 fwd
  gemm_gx<AM_CAT><<<gxg,256,0,stream>>>(nullptr, F_OF0, F_OB0, nullptr,
                                        e1_wih, e1_bih, F_GX, 2*HDIM);
  scan_kernel<false,false><<<NBLK,256,0,stream>>>(F_GX, F_T0, F_T1, e1_whh, e1_bhh, lengths, F_ENC);
  // encoder L1 bwd (accumulate)
  gemm_gx<AM_CAT><<<gxg,256,0,stream>>>(nullptr, F_OF0, F_OB0, nullptr,
                                        e1_wih+(u64)G3*2*HDIM, e1_bih+G3, F_GX, 2*HDIM);
  scan_kernel<true,true><<<NBLK,256,0,stream>>>(F_GX, F_T0, F_T1,
                                        e1_whh+(u64)G3*HDIM, e1_bhh+G3, lengths, F_ENC);
  // decoder
  gemm_gx<AM_DEC><<<gxg,256,0,stream>>>(dec_embed,0,0,tag_ids, d_wih, d_bih, F_GX, HDIM);
  decoder_kernel<<<NBLK,256,0,stream>>>(d_whh, d_bhh,
                                        d_wih+(u64)G3*HDIM, d_bih+G3,
                                        d_whh+(u64)G3*HDIM, d_bhh+G3,
                                        concat_w, concat_b, out_w, out_b,
                                        tag_ids, lengths, dout);
}